// Round 1
// 1078.701 us; speedup vs baseline: 1.4903x; 1.4903x over previous
//
#include <hip/hip_runtime.h>
#include <stdint.h>

#define BN 16
#define LN 512
#define HN 1024
#define KN 8192
#define TK 64
#define NTHREADS 512

typedef float  f32x4  __attribute__((ext_vector_type(4)));
typedef __bf16 bf16x8 __attribute__((ext_vector_type(8)));
typedef __bf16 bf16x4 __attribute__((ext_vector_type(4)));

// ---------------- async 16B global->LDS (DMA, no VGPR round trip) ----------
__device__ __forceinline__ void cp16(const void* g, void* l) {
  __builtin_amdgcn_global_load_lds(
      (const __attribute__((address_space(1))) unsigned int*)g,
      (__attribute__((address_space(3))) unsigned int*)l, 16, 0, 0);
}

// ---------------- prepass 1: W fp32 -> bf16 --------------------------------
__global__ void cvt_w(const float* __restrict__ W, __bf16* __restrict__ Wb) {
  const size_t i = (size_t)blockIdx.x * blockDim.x + threadIdx.x; // KN*HN/4 threads
  const float4 v = ((const float4*)W)[i];
  bf16x4 o; o[0] = (__bf16)v.x; o[1] = (__bf16)v.y; o[2] = (__bf16)v.z; o[3] = (__bf16)v.w;
  ((bf16x4*)Wb)[i] = o;
}

// ---------------- prepass 2: X -> bf16 X  and  bf16 X^T --------------------
// grid (128 = 8 l-tiles x 16 h-tiles, B), 256 threads, 64x64 tiles
__global__ void trans_x(const float* __restrict__ X, __bf16* __restrict__ Xb,
                        __bf16* __restrict__ Xt) {
  __shared__ __bf16 T[64][72];
  const int b  = blockIdx.y;
  const int l0 = (blockIdx.x & 7) * 64;
  const int h0 = (blockIdx.x >> 3) * 64;
  const int t  = threadIdx.x;
  #pragma unroll
  for (int it = 0; it < 4; ++it) {
    const int idx = it * 256 + t;            // 0..1023
    const int lr = idx >> 4, hc = (idx & 15) << 2;
    const float4 v = *(const float4*)(X + ((size_t)b * LN + l0 + lr) * HN + h0 + hc);
    bf16x4 o; o[0] = (__bf16)v.x; o[1] = (__bf16)v.y; o[2] = (__bf16)v.z; o[3] = (__bf16)v.w;
    *(bf16x4*)(Xb + ((size_t)b * LN + l0 + lr) * HN + h0 + hc) = o;
    *(bf16x4*)&T[lr][hc] = o;
  }
  __syncthreads();
  #pragma unroll
  for (int it = 0; it < 4; ++it) {
    const int idx = it * 256 + t;
    const int hr = idx >> 4, lg = (idx & 15) << 2;
    bf16x4 o;
    o[0] = T[lg + 0][hr]; o[1] = T[lg + 1][hr];
    o[2] = T[lg + 2][hr]; o[3] = T[lg + 3][hr];
    *(bf16x4*)(Xt + ((size_t)b * HN + h0 + hr) * LN + l0 + lg) = o;
  }
}

// ---------------- fused main kernel ----------------------------------------
// LDS tiles staged by global_load_lds are LINEAR (no pad allowed); bank
// conflicts on ds_read_b128 are fixed by XOR-swizzling the 16B slot index
// with (row&7), applying the inverse permutation on the global source
// address (both-sides-or-neither rule).
#define AT_LDA 520            // attn padded: 1040B row = free 2-way on reads

struct __align__(16) PhaseMem {
  __bf16 attn[TK][AT_LDA];    // 66,560 B
  __bf16 stage[512 * 64];     // 65,536 B  (p1: X-tile [l][h64] / p2: Xt-tile [h][l64])
  __bf16 wt[64 * 64];         //  8,192 B
  float redM[8][TK];
  float redS[8][TK];
  float Mf[TK];
  float Sinv[TK];
};
union SMem {
  PhaseMem p;
  float osm[TK * 516];        // 132,096 B f32 epilogue staging
};                            // total 144,896 B < 160 KiB

__global__ __launch_bounds__(NTHREADS, 1)
void mlattn_fused2(const __bf16* __restrict__ Wb, const __bf16* __restrict__ Xb,
                   const __bf16* __restrict__ Xt, const int* __restrict__ Mk,
                   float* __restrict__ out) {
  __shared__ SMem sm;
  const int t    = threadIdx.x;
  const int wv   = t >> 6;
  const int lane = t & 63;
  const int q    = lane >> 4;
  const int c    = lane & 15;
  const int b    = blockIdx.y;
  const int k0   = blockIdx.x * TK;
  const __bf16* Xbb = Xb + (size_t)b * LN * HN;
  const __bf16* Xtb = Xt + (size_t)b * HN * LN;
  const f32x4 fzero = {0.f, 0.f, 0.f, 0.f};

  // ===== Phase 1: S[64][512] = W_tile . Xb^T (contract h) ===================
  f32x4 acc[4][4];
  #pragma unroll
  for (int mt = 0; mt < 4; ++mt)
    #pragma unroll
    for (int nt = 0; nt < 4; ++nt) acc[mt][nt] = fzero;

  const int lw0 = wv * 64;

  for (int h0 = 0; h0 < HN; h0 += 64) {
    {  // W tile: 64 rows x 8 slots, 1 DMA/thread
      const int row = t >> 3, jj = t & 7;
      cp16(Wb + (size_t)(k0 + row) * HN + h0 + ((jj ^ (row & 7)) << 3),
           &sm.p.wt[t * 8]);
    }
    #pragma unroll
    for (int i = 0; i < 8; ++i) {  // X tile: 512 rows x 8 slots, 8 DMA/thread
      const int s = i * 512 + t;
      const int row = s >> 3, jj = s & 7;
      cp16(Xbb + (size_t)row * HN + h0 + ((jj ^ (row & 7)) << 3),
           &sm.p.stage[s * 8]);
    }
    __syncthreads();  // compiler drains vmcnt before s_barrier
    #pragma unroll
    for (int ks = 0; ks < 2; ++ks) {
      bf16x8 aF[4], bF[4];
      #pragma unroll
      for (int mt = 0; mt < 4; ++mt) {
        const int r = mt * 16 + c;
        aF[mt] = *(const bf16x8*)&sm.p.wt[r * 64 + (((ks * 4 + q) ^ (c & 7)) << 3)];
      }
      #pragma unroll
      for (int nt = 0; nt < 4; ++nt) {
        const int r = lw0 + nt * 16 + c;
        bF[nt] = *(const bf16x8*)&sm.p.stage[r * 64 + (((ks * 4 + q) ^ (c & 7)) << 3)];
      }
      #pragma unroll
      for (int mt = 0; mt < 4; ++mt)
        #pragma unroll
        for (int nt = 0; nt < 4; ++nt)
          acc[mt][nt] = __builtin_amdgcn_mfma_f32_16x16x32_bf16(aF[mt], bF[nt], acc[mt][nt], 0, 0, 0);
    }
    __syncthreads();
  }

  // ===== mask + softmax over l (unchanged, verified) ========================
  #pragma unroll
  for (int nt = 0; nt < 4; ++nt) {
    const int m = Mk[b * LN + lw0 + nt * 16 + c];
    if (!m) {
      #pragma unroll
      for (int mt = 0; mt < 4; ++mt)
        #pragma unroll
        for (int r = 0; r < 4; ++r) acc[mt][nt][r] = -1e30f;
    }
  }
  float pm[4][4];
  #pragma unroll
  for (int mt = 0; mt < 4; ++mt)
    #pragma unroll
    for (int r = 0; r < 4; ++r)
      pm[mt][r] = fmaxf(fmaxf(acc[mt][0][r], acc[mt][1][r]), fmaxf(acc[mt][2][r], acc[mt][3][r]));
  #pragma unroll
  for (int off = 1; off < 16; off <<= 1)
    #pragma unroll
    for (int mt = 0; mt < 4; ++mt)
      #pragma unroll
      for (int r = 0; r < 4; ++r)
        pm[mt][r] = fmaxf(pm[mt][r], __shfl_xor(pm[mt][r], off, 64));
  if (c == 0) {
    #pragma unroll
    for (int mt = 0; mt < 4; ++mt)
      #pragma unroll
      for (int r = 0; r < 4; ++r) sm.p.redM[wv][mt * 16 + q * 4 + r] = pm[mt][r];
  }
  __syncthreads();
  if (t < TK) {
    float m = sm.p.redM[0][t];
    #pragma unroll
    for (int w = 1; w < 8; ++w) m = fmaxf(m, sm.p.redM[w][t]);
    sm.p.Mf[t] = m;
  }
  __syncthreads();

  float ps[4][4];
  #pragma unroll
  for (int mt = 0; mt < 4; ++mt)
    #pragma unroll
    for (int r = 0; r < 4; ++r) {
      const float M = sm.p.Mf[mt * 16 + q * 4 + r];
      float s = 0.f;
      #pragma unroll
      for (int nt = 0; nt < 4; ++nt) {
        const float e = __expf(acc[mt][nt][r] - M);
        acc[mt][nt][r] = e;
        s += e;
      }
      ps[mt][r] = s;
    }
  #pragma unroll
  for (int off = 1; off < 16; off <<= 1)
    #pragma unroll
    for (int mt = 0; mt < 4; ++mt)
      #pragma unroll
      for (int r = 0; r < 4; ++r) ps[mt][r] += __shfl_xor(ps[mt][r], off, 64);
  if (c == 0) {
    #pragma unroll
    for (int mt = 0; mt < 4; ++mt)
      #pragma unroll
      for (int r = 0; r < 4; ++r) sm.p.redS[wv][mt * 16 + q * 4 + r] = ps[mt][r];
  }
  __syncthreads();
  if (t < TK) {
    float s = 0.f;
    #pragma unroll
    for (int w = 0; w < 8; ++w) s += sm.p.redS[w][t];
    sm.p.Sinv[t] = 1.f / s;
  }
  __syncthreads();

  #pragma unroll
  for (int mt = 0; mt < 4; ++mt)
    #pragma unroll
    for (int r = 0; r < 4; ++r) {
      const int row = mt * 16 + q * 4 + r;
      const float inv = sm.p.Sinv[row];
      #pragma unroll
      for (int nt = 0; nt < 4; ++nt)
        sm.p.attn[row][lw0 + nt * 16 + c] = (__bf16)(acc[mt][nt][r] * inv);
    }
  // attn writes are made visible by the barrier after the first phase-2 stage

  // ===== Phase 2: O[64][1024] = attn . Xb (contract l), B-frags from X^T ====
  const int wM = wv >> 2;   // k-half (32 rows)
  const int wN = wv & 3;    // h-quarter (128 of the staged 512)
  f32x4 acc2[2][16];
  #pragma unroll
  for (int i = 0; i < 2; ++i)
    #pragma unroll
    for (int j = 0; j < 16; ++j) acc2[i][j] = fzero;

  for (int lc = 0; lc < 8; ++lc) {
    const int l0c = lc * 64;
    #pragma unroll
    for (int hh = 0; hh < 2; ++hh) {
      #pragma unroll
      for (int i = 0; i < 8; ++i) {  // Xt tile: 512 h-rows x 8 l-slots
        const int s = i * 512 + t;
        const int row = s >> 3, jj = s & 7;
        cp16(Xtb + (size_t)(hh * 512 + row) * LN + l0c + ((jj ^ (row & 7)) << 3),
             &sm.p.stage[s * 8]);
      }
      __syncthreads();
      #pragma unroll
      for (int ks = 0; ks < 2; ++ks) {
        bf16x8 aF2[2], bF2[8];
        #pragma unroll
        for (int mt = 0; mt < 2; ++mt)
          aF2[mt] = *(const bf16x8*)&sm.p.attn[wM * 32 + mt * 16 + c][l0c + ks * 32 + q * 8];
        #pragma unroll
        for (int nt = 0; nt < 8; ++nt) {
          const int r = wN * 128 + nt * 16 + c;
          bF2[nt] = *(const bf16x8*)&sm.p.stage[r * 64 + (((ks * 4 + q) ^ (c & 7)) << 3)];
        }
        #pragma unroll
        for (int mt = 0; mt < 2; ++mt)
          #pragma unroll
          for (int nt = 0; nt < 8; ++nt)
            acc2[mt][hh * 8 + nt] =
                __builtin_amdgcn_mfma_f32_16x16x32_bf16(aF2[mt], bF2[nt], acc2[mt][hh * 8 + nt], 0, 0, 0);
      }
      __syncthreads();
    }
  }

  // ===== epilogue: LDS round-trip -> full-line dwordx4 stores ===============
  float* outb = out + ((size_t)b * KN + k0) * HN;
  #pragma unroll
  for (int hh = 0; hh < 2; ++hh) {
    if (hh) __syncthreads();   // prior chunk's LDS reads done before overwrite
    #pragma unroll
    for (int mt = 0; mt < 2; ++mt)
      #pragma unroll
      for (int nt = 0; nt < 8; ++nt) {
        const int hl = wN * 128 + nt * 16 + c;
        #pragma unroll
        for (int r = 0; r < 4; ++r) {
          const int krow = wM * 32 + mt * 16 + q * 4 + r;
          sm.osm[krow * 516 + hl] = acc2[mt][hh * 8 + nt][r];
        }
      }
    __syncthreads();
    #pragma unroll
    for (int i = 0; i < 16; ++i) {
      const int s = i * 512 + t;
      const int row = s >> 7, col4 = s & 127;   // wave: 1 KB contiguous store
      *(f32x4*)(outb + (size_t)row * HN + hh * 512 + (col4 << 2)) =
          *(const f32x4*)&sm.osm[row * 516 + (col4 << 2)];
    }
  }
}

// ---------------- fallback (previous verified kernel) ----------------------
#define XT_LDA 72
#define WT_LDA 72
#define AT_LDA_O 520
#define X2_LDA 72

struct __align__(16) SMemOld {
  __bf16 attn[TK][AT_LDA_O];
  union {
    struct { __bf16 xt[LN][XT_LDA]; __bf16 wt[TK][WT_LDA]; } p1;
    __bf16 x2[512][X2_LDA];
  } u;
  float redM[8][TK];
  float redS[8][TK];
  float Mf[TK];
  float Sinv[TK];
};

__device__ __forceinline__ bf16x4 cvt4o(float4 v) {
  bf16x4 r;
  r[0] = (__bf16)v.x; r[1] = (__bf16)v.y; r[2] = (__bf16)v.z; r[3] = (__bf16)v.w;
  return r;
}

__global__ __launch_bounds__(NTHREADS, 2)
void mlattn_fused(const float* __restrict__ X, const int* __restrict__ Mk,
                  const float* __restrict__ W, float* __restrict__ out) {
  __shared__ SMemOld sm;
  const int t    = threadIdx.x;
  const int wv   = t >> 6;
  const int lane = t & 63;
  const int q    = lane >> 4;
  const int c    = lane & 15;
  const int b    = blockIdx.y;
  const int k0   = blockIdx.x * TK;
  const float* Xb = X + (size_t)b * LN * HN;
  const f32x4 fzero = {0.f, 0.f, 0.f, 0.f};

  f32x4 acc[4][4];
  #pragma unroll
  for (int mt = 0; mt < 4; ++mt)
    #pragma unroll
    for (int nt = 0; nt < 4; ++nt) acc[mt][nt] = fzero;

  const int lw0 = wv * 64;
  const int sr  = t >> 4;
  const int sc  = t & 15;

  for (int h0 = 0; h0 < HN; h0 += 64) {
    #pragma unroll
    for (int p = 0; p < 2; ++p) {
      const int row = p * 32 + sr;
      float4 v = *(const float4*)(W + (size_t)(k0 + row) * HN + h0 + sc * 4);
      *(bf16x4*)&sm.u.p1.wt[row][sc * 4] = cvt4o(v);
    }
    #pragma unroll
    for (int p = 0; p < 16; ++p) {
      const int row = p * 32 + sr;
      float4 v = *(const float4*)(Xb + (size_t)row * HN + h0 + sc * 4);
      *(bf16x4*)&sm.u.p1.xt[row][sc * 4] = cvt4o(v);
    }
    __syncthreads();
    #pragma unroll
    for (int ks = 0; ks < 2; ++ks) {
      bf16x8 aF[4], bF[4];
      #pragma unroll
      for (int mt = 0; mt < 4; ++mt)
        aF[mt] = *(const bf16x8*)&sm.u.p1.wt[mt * 16 + c][ks * 32 + q * 8];
      #pragma unroll
      for (int nt = 0; nt < 4; ++nt)
        bF[nt] = *(const bf16x8*)&sm.u.p1.xt[lw0 + nt * 16 + c][ks * 32 + q * 8];
      #pragma unroll
      for (int mt = 0; mt < 4; ++mt)
        #pragma unroll
        for (int nt = 0; nt < 4; ++nt)
          acc[mt][nt] = __builtin_amdgcn_mfma_f32_16x16x32_bf16(aF[mt], bF[nt], acc[mt][nt], 0, 0, 0);
    }
    __syncthreads();
  }

  #pragma unroll
  for (int nt = 0; nt < 4; ++nt) {
    const int m = Mk[b * LN + lw0 + nt * 16 + c];
    if (!m) {
      #pragma unroll
      for (int mt = 0; mt < 4; ++mt)
        #pragma unroll
        for (int r = 0; r < 4; ++r) acc[mt][nt][r] = -1e30f;
    }
  }

  float pm[4][4];
  #pragma unroll
  for (int mt = 0; mt < 4; ++mt)
    #pragma unroll
    for (int r = 0; r < 4; ++r)
      pm[mt][r] = fmaxf(fmaxf(acc[mt][0][r], acc[mt][1][r]), fmaxf(acc[mt][2][r], acc[mt][3][r]));
  #pragma unroll
  for (int off = 1; off < 16; off <<= 1)
    #pragma unroll
    for (int mt = 0; mt < 4; ++mt)
      #pragma unroll
      for (int r = 0; r < 4; ++r)
        pm[mt][r] = fmaxf(pm[mt][r], __shfl_xor(pm[mt][r], off, 64));
  if (c == 0) {
    #pragma unroll
    for (int mt = 0; mt < 4; ++mt)
      #pragma unroll
      for (int r = 0; r < 4; ++r) sm.redM[wv][mt * 16 + q * 4 + r] = pm[mt][r];
  }
  __syncthreads();
  if (t < TK) {
    float m = sm.redM[0][t];
    #pragma unroll
    for (int w = 1; w < 8; ++w) m = fmaxf(m, sm.redM[w][t]);
    sm.Mf[t] = m;
  }
  __syncthreads();

  float ps[4][4];
  #pragma unroll
  for (int mt = 0; mt < 4; ++mt)
    #pragma unroll
    for (int r = 0; r < 4; ++r) {
      const float M = sm.Mf[mt * 16 + q * 4 + r];
      float s = 0.f;
      #pragma unroll
      for (int nt = 0; nt < 4; ++nt) {
        const float e = __expf(acc[mt][nt][r] - M);
        acc[mt][nt][r] = e;
        s += e;
      }
      ps[mt][r] = s;
    }
  #pragma unroll
  for (int off = 1; off < 16; off <<= 1)
    #pragma unroll
    for (int mt = 0; mt < 4; ++mt)
      #pragma unroll
      for (int r = 0; r < 4; ++r) ps[mt][r] += __shfl_xor(ps[mt][r], off, 64);
  if (c == 0) {
    #pragma unroll
    for (int mt = 0; mt < 4; ++mt)
      #pragma unroll
      for (int r = 0; r < 4; ++r) sm.redS[wv][mt * 16 + q * 4 + r] = ps[mt][r];
  }
  __syncthreads();
  if (t < TK) {
    float s = 0.f;
    #pragma unroll
    for (int w = 0; w < 8; ++w) s += sm.redS[w][t];
    sm.Sinv[t] = 1.f / s;
  }
  __syncthreads();

  #pragma unroll
  for (int mt = 0; mt < 4; ++mt)
    #pragma unroll
    for (int r = 0; r < 4; ++r) {
      const int row = mt * 16 + q * 4 + r;
      const float inv = sm.Sinv[row];
      #pragma unroll
      for (int nt = 0; nt < 4; ++nt)
        sm.attn[row][lw0 + nt * 16 + c] = (__bf16)(acc[mt][nt][r] * inv);
    }

  const int wM = wv >> 2;
  const int wN = wv & 3;
  f32x4 acc2[2][16];
  #pragma unroll
  for (int i = 0; i < 2; ++i)
    #pragma unroll
    for (int j = 0; j < 16; ++j) acc2[i][j] = fzero;

  for (int lc = 0; lc < 8; ++lc) {
    const int l0c = lc * 64;
    #pragma unroll
    for (int hh = 0; hh < 2; ++hh) {
      __syncthreads();
      {
        const float* xcol = Xb + (size_t)hh * 512 + t;
        #pragma unroll
        for (int u = 0; u < 16; ++u) {
          const int l = l0c + u * 4;
          const float d0 = xcol[(size_t)(l + 0) * HN];
          const float d1 = xcol[(size_t)(l + 1) * HN];
          const float d2 = xcol[(size_t)(l + 2) * HN];
          const float d3 = xcol[(size_t)(l + 3) * HN];
          bf16x4 p;
          p[0] = (__bf16)d0; p[1] = (__bf16)d1; p[2] = (__bf16)d2; p[3] = (__bf16)d3;
          *(bf16x4*)&sm.u.x2[t][u * 4] = p;
        }
      }
      __syncthreads();
      #pragma unroll
      for (int ks = 0; ks < 2; ++ks) {
        bf16x8 aF2[2], bF2[8];
        #pragma unroll
        for (int mt = 0; mt < 2; ++mt)
          aF2[mt] = *(const bf16x8*)&sm.attn[wM * 32 + mt * 16 + c][l0c + ks * 32 + q * 8];
        #pragma unroll
        for (int nt = 0; nt < 8; ++nt)
          bF2[nt] = *(const bf16x8*)&sm.u.x2[wN * 128 + nt * 16 + c][ks * 32 + q * 8];
        #pragma unroll
        for (int mt = 0; mt < 2; ++mt)
          #pragma unroll
          for (int nt = 0; nt < 8; ++nt)
            acc2[mt][hh * 8 + nt] =
                __builtin_amdgcn_mfma_f32_16x16x32_bf16(aF2[mt], bF2[nt], acc2[mt][hh * 8 + nt], 0, 0, 0);
      }
    }
  }

  float* outb = out + ((size_t)b * KN + k0) * HN;
  #pragma unroll
  for (int mt = 0; mt < 2; ++mt) {
    #pragma unroll
    for (int j = 0; j < 16; ++j) {
      const int hh = j >> 3, nt = j & 7;
      const int h = hh * 512 + wN * 128 + nt * 16 + c;
      #pragma unroll
      for (int r = 0; r < 4; ++r) {
        const int krow = wM * 32 + mt * 16 + q * 4 + r;
        outb[(size_t)krow * HN + h] = acc2[mt][j][r];
      }
    }
  }
}

// ---------------- launch ----------------------------------------------------
extern "C" void kernel_launch(void* const* d_in, const int* in_sizes, int n_in,
                              void* d_out, int out_size, void* d_ws, size_t ws_size,
                              hipStream_t stream) {
  (void)in_sizes; (void)n_in; (void)out_size;
  const float* X = (const float*)d_in[0];
  const int* Mk = (const int*)d_in[1];
  const float* W = (const float*)d_in[2];
  float* out = (float*)d_out;

  const size_t need = ((size_t)KN * HN + 2 * (size_t)BN * LN * HN) * sizeof(__bf16);
  if (d_ws == nullptr || ws_size < need) {
    dim3 grid(KN / TK, BN);
    mlattn_fused<<<grid, NTHREADS, 0, stream>>>(X, Mk, W, out);
    return;
  }

  __bf16* Wb = (__bf16*)d_ws;                       // 16 MB
  __bf16* Xbb = Wb + (size_t)KN * HN;               // 16 MB
  __bf16* Xtb = Xbb + (size_t)BN * LN * HN;         // 16 MB

  cvt_w<<<(KN * HN / 4) / 256, 256, 0, stream>>>(W, Wb);
  trans_x<<<dim3(128, BN), 256, 0, stream>>>(X, Xbb, Xtb);
  mlattn_fused2<<<dim3(KN / TK, BN), NTHREADS, 0, stream>>>(Wb, Xbb, Xtb, Mk, out);
}

// Round 2
// 1001.276 us; speedup vs baseline: 1.6056x; 1.0773x over previous
//
#include <hip/hip_runtime.h>
#include <stdint.h>

#define BN 16
#define LN 512
#define HN 1024
#define KN 8192
#define TK 64
#define NTHREADS 512

typedef float  f32x4  __attribute__((ext_vector_type(4)));
typedef __bf16 bf16x8 __attribute__((ext_vector_type(8)));
typedef __bf16 bf16x4 __attribute__((ext_vector_type(4)));

// ---------------- async 16B global->LDS (DMA, no VGPR round trip) ----------
__device__ __forceinline__ void cp16(const void* g, void* l) {
  __builtin_amdgcn_global_load_lds(
      (const __attribute__((address_space(1))) unsigned int*)g,
      (__attribute__((address_space(3))) unsigned int*)l, 16, 0, 0);
}

// ---------------- prepass 1: W fp32 -> bf16 --------------------------------
__global__ void cvt_w(const float* __restrict__ W, __bf16* __restrict__ Wb) {
  const size_t i = (size_t)blockIdx.x * blockDim.x + threadIdx.x; // KN*HN/4 threads
  const float4 v = ((const float4*)W)[i];
  bf16x4 o; o[0] = (__bf16)v.x; o[1] = (__bf16)v.y; o[2] = (__bf16)v.z; o[3] = (__bf16)v.w;
  ((bf16x4*)Wb)[i] = o;
}

// ---------------- prepass 2: X -> bf16 X  and  bf16 X^T --------------------
__global__ void trans_x(const float* __restrict__ X, __bf16* __restrict__ Xb,
                        __bf16* __restrict__ Xt) {
  __shared__ __bf16 T[64][72];
  const int b  = blockIdx.y;
  const int l0 = (blockIdx.x & 7) * 64;
  const int h0 = (blockIdx.x >> 3) * 64;
  const int t  = threadIdx.x;
  #pragma unroll
  for (int it = 0; it < 4; ++it) {
    const int idx = it * 256 + t;            // 0..1023
    const int lr = idx >> 4, hc = (idx & 15) << 2;
    const float4 v = *(const float4*)(X + ((size_t)b * LN + l0 + lr) * HN + h0 + hc);
    bf16x4 o; o[0] = (__bf16)v.x; o[1] = (__bf16)v.y; o[2] = (__bf16)v.z; o[3] = (__bf16)v.w;
    *(bf16x4*)(Xb + ((size_t)b * LN + l0 + lr) * HN + h0 + hc) = o;
    *(bf16x4*)&T[lr][hc] = o;
  }
  __syncthreads();
  #pragma unroll
  for (int it = 0; it < 4; ++it) {
    const int idx = it * 256 + t;
    const int hr = idx >> 4, lg = (idx & 15) << 2;
    bf16x4 o;
    o[0] = T[lg + 0][hr]; o[1] = T[lg + 1][hr];
    o[2] = T[lg + 2][hr]; o[3] = T[lg + 3][hr];
    *(bf16x4*)(Xt + ((size_t)b * HN + h0 + hr) * LN + l0 + lg) = o;
  }
}

// ---------------- fused main kernel (double-buffered pipeline) -------------
// Staged LDS tiles are LINEAR (global_load_lds constraint); ds_read bank
// conflicts fixed by XOR-swizzling the 16B slot index, with the inverse
// permutation applied to the GLOBAL source address (both-sides rule).
//   phase-1 (8 slots/row):  jj' = jj ^ (row&7)
//   phase-2 (4 slots/row):  jj' = jj ^ ((row>>1)&3)   (slot%8 spans 8 values)
#define P2_AT_LDA 520

struct __align__(16) P1Mem {
  __bf16 xs[2][512 * 64];     // 2 x 65,536 B
  __bf16 wt[2][64 * 64];      // 2 x  8,192 B   => 147,456 B
};
struct __align__(16) P2Mem {
  __bf16 attn[TK][P2_AT_LDA]; // 66,560 B
  __bf16 xt[2][512 * 32];     // 2 x 32,768 B   => 132,096 B
};
struct __align__(16) SMem {
  union {
    P1Mem p1;
    P2Mem p2;
    float osm[TK * 516];      // 132,096 B epilogue staging
  } u;
  float redM[8][TK];
  float redS[8][TK];
  float Mf[TK];
  float Sinv[TK];
};                            // 152,064 B < 160 KiB

__global__ __launch_bounds__(NTHREADS, 1)
void mlattn_fused2(const __bf16* __restrict__ Wb, const __bf16* __restrict__ Xb,
                   const __bf16* __restrict__ Xt, const int* __restrict__ Mk,
                   float* __restrict__ out) {
  __shared__ SMem sm;
  const int t    = threadIdx.x;
  const int wv   = t >> 6;
  const int lane = t & 63;
  const int q    = lane >> 4;
  const int c    = lane & 15;
  const int b    = blockIdx.y;
  const int k0   = blockIdx.x * TK;
  const __bf16* Xbb = Xb + (size_t)b * LN * HN;
  const __bf16* Xtb = Xt + (size_t)b * HN * LN;
  const f32x4 fzero = {0.f, 0.f, 0.f, 0.f};

  // -------- per-thread staging bases (swizzle folded into global src) ------
  // phase 1: slot s = i*512+t, row = s>>3 = i*64 + (t>>3), jj = t&7
  const int tr8 = t >> 3, tc8 = t & 7;
  const int colOff1 = ((tc8 ^ (tr8 & 7)) << 3);
  const __bf16* xsrc = Xbb + (size_t)tr8 * HN + colOff1;
  const __bf16* wsrc = Wb + (size_t)(k0 + tr8) * HN + colOff1;
  // phase 2: slot s = i*512+t, row = s>>2 = i*128 + (t>>2), jj = t&3
  const int tr4 = t >> 2, tc4 = t & 3;
  const int colOff2 = ((tc4 ^ ((t >> 3) & 3)) << 3);
  const __bf16* tsrc = Xtb + (size_t)tr4 * LN + colOff2;

  // ===== Phase 1: S[64][512] = W_tile . Xb^T (contract h), dbuf pipeline ===
  f32x4 acc[4][4];
  #pragma unroll
  for (int mt = 0; mt < 4; ++mt)
    #pragma unroll
    for (int nt = 0; nt < 4; ++nt) acc[mt][nt] = fzero;

  const int lw0 = wv * 64;

  // prologue: stage tile 0 into buffer 0
  {
    cp16(wsrc, &sm.u.p1.wt[0][t * 8]);
    #pragma unroll
    for (int i = 0; i < 8; ++i)
      cp16(xsrc + (size_t)i * 64 * HN, &sm.u.p1.xs[0][(i * 512 + t) * 8]);
  }
  __syncthreads();

  int cur = 0;
  for (int tt = 0; tt < 16; ++tt) {
    // stage next tile into the other buffer (in flight during MFMA)
    if (tt + 1 < 16) {
      const int h0 = (tt + 1) * 64;
      cp16(wsrc + h0, &sm.u.p1.wt[cur ^ 1][t * 8]);
      #pragma unroll
      for (int i = 0; i < 8; ++i)
        cp16(xsrc + (size_t)i * 64 * HN + h0, &sm.u.p1.xs[cur ^ 1][(i * 512 + t) * 8]);
    }
    // compute current buffer
    #pragma unroll
    for (int ks = 0; ks < 2; ++ks) {
      bf16x8 aF[4], bF[4];
      #pragma unroll
      for (int mt = 0; mt < 4; ++mt) {
        const int r = mt * 16 + c;
        aF[mt] = *(const bf16x8*)&sm.u.p1.wt[cur][r * 64 + (((ks * 4 + q) ^ (c & 7)) << 3)];
      }
      #pragma unroll
      for (int nt = 0; nt < 4; ++nt) {
        const int r = lw0 + nt * 16 + c;
        bF[nt] = *(const bf16x8*)&sm.u.p1.xs[cur][r * 64 + (((ks * 4 + q) ^ (c & 7)) << 3)];
      }
      #pragma unroll
      for (int mt = 0; mt < 4; ++mt)
        #pragma unroll
        for (int nt = 0; nt < 4; ++nt)
          acc[mt][nt] = __builtin_amdgcn_mfma_f32_16x16x32_bf16(aF[mt], bF[nt], acc[mt][nt], 0, 0, 0);
    }
    __syncthreads();   // drains next-tile vmcnt + protects buffer swap
    cur ^= 1;
  }

  // prefetch phase-2 tile 0 NOW (lands during softmax; p1 buffers are dead)
  {
    #pragma unroll
    for (int i = 0; i < 4; ++i)
      cp16(tsrc + (size_t)i * 128 * LN, &sm.u.p2.xt[0][(i * 512 + t) * 8]);
  }

  // ===== mask + softmax over l (verified) ===================================
  #pragma unroll
  for (int nt = 0; nt < 4; ++nt) {
    const int m = Mk[b * LN + lw0 + nt * 16 + c];
    if (!m) {
      #pragma unroll
      for (int mt = 0; mt < 4; ++mt)
        #pragma unroll
        for (int r = 0; r < 4; ++r) acc[mt][nt][r] = -1e30f;
    }
  }
  float pm[4][4];
  #pragma unroll
  for (int mt = 0; mt < 4; ++mt)
    #pragma unroll
    for (int r = 0; r < 4; ++r)
      pm[mt][r] = fmaxf(fmaxf(acc[mt][0][r], acc[mt][1][r]), fmaxf(acc[mt][2][r], acc[mt][3][r]));
  #pragma unroll
  for (int off = 1; off < 16; off <<= 1)
    #pragma unroll
    for (int mt = 0; mt < 4; ++mt)
      #pragma unroll
      for (int r = 0; r < 4; ++r)
        pm[mt][r] = fmaxf(pm[mt][r], __shfl_xor(pm[mt][r], off, 64));
  if (c == 0) {
    #pragma unroll
    for (int mt = 0; mt < 4; ++mt)
      #pragma unroll
      for (int r = 0; r < 4; ++r) sm.redM[wv][mt * 16 + q * 4 + r] = pm[mt][r];
  }
  __syncthreads();
  if (t < TK) {
    float m = sm.redM[0][t];
    #pragma unroll
    for (int w = 1; w < 8; ++w) m = fmaxf(m, sm.redM[w][t]);
    sm.Mf[t] = m;
  }
  __syncthreads();

  float ps[4][4];
  #pragma unroll
  for (int mt = 0; mt < 4; ++mt)
    #pragma unroll
    for (int r = 0; r < 4; ++r) {
      const float M = sm.Mf[mt * 16 + q * 4 + r];
      float s = 0.f;
      #pragma unroll
      for (int nt = 0; nt < 4; ++nt) {
        const float e = __expf(acc[mt][nt][r] - M);
        acc[mt][nt][r] = e;
        s += e;
      }
      ps[mt][r] = s;
    }
  #pragma unroll
  for (int off = 1; off < 16; off <<= 1)
    #pragma unroll
    for (int mt = 0; mt < 4; ++mt)
      #pragma unroll
      for (int r = 0; r < 4; ++r) ps[mt][r] += __shfl_xor(ps[mt][r], off, 64);
  if (c == 0) {
    #pragma unroll
    for (int mt = 0; mt < 4; ++mt)
      #pragma unroll
      for (int r = 0; r < 4; ++r) sm.redS[wv][mt * 16 + q * 4 + r] = ps[mt][r];
  }
  __syncthreads();
  if (t < TK) {
    float s = 0.f;
    #pragma unroll
    for (int w = 0; w < 8; ++w) s += sm.redS[w][t];
    sm.Sinv[t] = 1.f / s;
  }
  __syncthreads();

  // normalized attn -> LDS (A-operand layout, full 64x512 tile)
  #pragma unroll
  for (int mt = 0; mt < 4; ++mt)
    #pragma unroll
    for (int r = 0; r < 4; ++r) {
      const int row = mt * 16 + q * 4 + r;
      const float inv = sm.Sinv[row];
      #pragma unroll
      for (int nt = 0; nt < 4; ++nt)
        sm.u.p2.attn[row][lw0 + nt * 16 + c] = (__bf16)(acc[mt][nt][r] * inv);
    }
  __syncthreads();   // attn visible; xt[0] stage drained (vmcnt(0) at barrier)

  // ===== Phase 2: O[64][1024] = attn . Xb (contract l), dbuf pipeline ======
  // step s: l-chunk = (s>>1)*32, h-half = s&1
  const int wM = wv >> 2;
  const int wN = wv & 3;
  const int swq8 = ((q ^ ((c >> 1) & 3)) << 3);   // phase-2 read swizzle
  f32x4 acc2[2][16];
  #pragma unroll
  for (int i = 0; i < 2; ++i)
    #pragma unroll
    for (int j = 0; j < 16; ++j) acc2[i][j] = fzero;

  cur = 0;
  for (int s = 0; s < 32; ++s) {
    if (s + 1 < 32) {
      const int sn = s + 1;
      const __bf16* src = tsrc + (size_t)((sn & 1) * 512) * LN + ((sn >> 1) << 5);
      #pragma unroll
      for (int i = 0; i < 4; ++i)
        cp16(src + (size_t)i * 128 * LN, &sm.u.p2.xt[cur ^ 1][(i * 512 + t) * 8]);
    }
    const int l0c = (s >> 1) << 5;
    const int hh  = s & 1;
    bf16x8 aF2[2], bF2[8];
    #pragma unroll
    for (int mt = 0; mt < 2; ++mt)
      aF2[mt] = *(const bf16x8*)&sm.u.p2.attn[wM * 32 + mt * 16 + c][l0c + q * 8];
    #pragma unroll
    for (int nt = 0; nt < 8; ++nt) {
      const int r = wN * 128 + nt * 16 + c;
      bF2[nt] = *(const bf16x8*)&sm.u.p2.xt[cur][r * 32 + swq8];
    }
    #pragma unroll
    for (int mt = 0; mt < 2; ++mt)
      #pragma unroll
      for (int nt = 0; nt < 8; ++nt)
        acc2[mt][hh * 8 + nt] =
            __builtin_amdgcn_mfma_f32_16x16x32_bf16(aF2[mt], bF2[nt], acc2[mt][hh * 8 + nt], 0, 0, 0);
    __syncthreads();
    cur ^= 1;
  }

  // ===== epilogue: LDS round-trip -> full-line dwordx4 stores ===============
  float* outb = out + ((size_t)b * KN + k0) * HN;
  #pragma unroll
  for (int hh = 0; hh < 2; ++hh) {
    if (hh) __syncthreads();
    #pragma unroll
    for (int mt = 0; mt < 2; ++mt)
      #pragma unroll
      for (int nt = 0; nt < 8; ++nt) {
        const int hl = wN * 128 + nt * 16 + c;
        #pragma unroll
        for (int r = 0; r < 4; ++r) {
          const int krow = wM * 32 + mt * 16 + q * 4 + r;
          sm.u.osm[krow * 516 + hl] = acc2[mt][hh * 8 + nt][r];
        }
      }
    __syncthreads();
    #pragma unroll
    for (int i = 0; i < 16; ++i) {
      const int s = i * 512 + t;
      const int row = s >> 7, col4 = s & 127;
      *(f32x4*)(outb + (size_t)row * HN + hh * 512 + (col4 << 2)) =
          *(const f32x4*)&sm.u.osm[row * 516 + (col4 << 2)];
    }
  }
}

// ---------------- fallback (previous verified kernel) ----------------------
#define XT_LDA 72
#define WT_LDA 72
#define AT_LDA_O 520
#define X2_LDA 72

struct __align__(16) SMemOld {
  __bf16 attn[TK][AT_LDA_O];
  union {
    struct { __bf16 xt[LN][XT_LDA]; __bf16 wt[TK][WT_LDA]; } p1;
    __bf16 x2[512][X2_LDA];
  } u;
  float redM[8][TK];
  float redS[8][TK];
  float Mf[TK];
  float Sinv[TK];
};

__device__ __forceinline__ bf16x4 cvt4o(float4 v) {
  bf16x4 r;
  r[0] = (__bf16)v.x; r[1] = (__bf16)v.y; r[2] = (__bf16)v.z; r[3] = (__bf16)v.w;
  return r;
}

__global__ __launch_bounds__(NTHREADS, 2)
void mlattn_fused(const float* __restrict__ X, const int* __restrict__ Mk,
                  const float* __restrict__ W, float* __restrict__ out) {
  __shared__ SMemOld sm;
  const int t    = threadIdx.x;
  const int wv   = t >> 6;
  const int lane = t & 63;
  const int q    = lane >> 4;
  const int c    = lane & 15;
  const int b    = blockIdx.y;
  const int k0   = blockIdx.x * TK;
  const float* Xb = X + (size_t)b * LN * HN;
  const f32x4 fzero = {0.f, 0.f, 0.f, 0.f};

  f32x4 acc[4][4];
  #pragma unroll
  for (int mt = 0; mt < 4; ++mt)
    #pragma unroll
    for (int nt = 0; nt < 4; ++nt) acc[mt][nt] = fzero;

  const int lw0 = wv * 64;
  const int sr  = t >> 4;
  const int sc  = t & 15;

  for (int h0 = 0; h0 < HN; h0 += 64) {
    #pragma unroll
    for (int p = 0; p < 2; ++p) {
      const int row = p * 32 + sr;
      float4 v = *(const float4*)(W + (size_t)(k0 + row) * HN + h0 + sc * 4);
      *(bf16x4*)&sm.u.p1.wt[row][sc * 4] = cvt4o(v);
    }
    #pragma unroll
    for (int p = 0; p < 16; ++p) {
      const int row = p * 32 + sr;
      float4 v = *(const float4*)(Xb + (size_t)row * HN + h0 + sc * 4);
      *(bf16x4*)&sm.u.p1.xt[row][sc * 4] = cvt4o(v);
    }
    __syncthreads();
    #pragma unroll
    for (int ks = 0; ks < 2; ++ks) {
      bf16x8 aF[4], bF[4];
      #pragma unroll
      for (int mt = 0; mt < 4; ++mt)
        aF[mt] = *(const bf16x8*)&sm.u.p1.wt[mt * 16 + c][ks * 32 + q * 8];
      #pragma unroll
      for (int nt = 0; nt < 4; ++nt)
        bF[nt] = *(const bf16x8*)&sm.u.p1.xt[lw0 + nt * 16 + c][ks * 32 + q * 8];
      #pragma unroll
      for (int mt = 0; mt < 4; ++mt)
        #pragma unroll
        for (int nt = 0; nt < 4; ++nt)
          acc[mt][nt] = __builtin_amdgcn_mfma_f32_16x16x32_bf16(aF[mt], bF[nt], acc[mt][nt], 0, 0, 0);
    }
    __syncthreads();
  }

  #pragma unroll
  for (int nt = 0; nt < 4; ++nt) {
    const int m = Mk[b * LN + lw0 + nt * 16 + c];
    if (!m) {
      #pragma unroll
      for (int mt = 0; mt < 4; ++mt)
        #pragma unroll
        for (int r = 0; r < 4; ++r) acc[mt][nt][r] = -1e30f;
    }
  }

  float pm[4][4];
  #pragma unroll
  for (int mt = 0; mt < 4; ++mt)
    #pragma unroll
    for (int r = 0; r < 4; ++r)
      pm[mt][r] = fmaxf(fmaxf(acc[mt][0][r], acc[mt][1][r]), fmaxf(acc[mt][2][r], acc[mt][3][r]));
  #pragma unroll
  for (int off = 1; off < 16; off <<= 1)
    #pragma unroll
    for (int mt = 0; mt < 4; ++mt)
      #pragma unroll
      for (int r = 0; r < 4; ++r)
        pm[mt][r] = fmaxf(pm[mt][r], __shfl_xor(pm[mt][r], off, 64));
  if (c == 0) {
    #pragma unroll
    for (int mt = 0; mt < 4; ++mt)
      #pragma unroll
      for (int r = 0; r < 4; ++r) sm.redM[wv][mt * 16 + q * 4 + r] = pm[mt][r];
  }
  __syncthreads();
  if (t < TK) {
    float m = sm.redM[0][t];
    #pragma unroll
    for (int w = 1; w < 8; ++w) m = fmaxf(m, sm.redM[w][t]);
    sm.Mf[t] = m;
  }
  __syncthreads();

  float ps[4][4];
  #pragma unroll
  for (int mt = 0; mt < 4; ++mt)
    #pragma unroll
    for (int r = 0; r < 4; ++r) {
      const float M = sm.Mf[mt * 16 + q * 4 + r];
      float s = 0.f;
      #pragma unroll
      for (int nt = 0; nt < 4; ++nt) {
        const float e = __expf(acc[mt][nt][r] - M);
        acc[mt][nt][r] = e;
        s += e;
      }
      ps[mt][r] = s;
    }
  #pragma unroll
  for (int off = 1; off < 16; off <<= 1)
    #pragma unroll
    for (int mt = 0; mt < 4; ++mt)
      #pragma unroll
      for (int r = 0; r < 4; ++r) ps[mt][r] += __shfl_xor(ps[mt][r], off, 64);
  if (c == 0) {
    #pragma unroll
    for (int mt = 0; mt < 4; ++mt)
      #pragma unroll
      for (int r = 0; r < 4; ++r) sm.redS[wv][mt * 16 + q * 4 + r] = ps[mt][r];
  }
  __syncthreads();
  if (t < TK) {
    float s = 0.f;
    #pragma unroll
    for (int w = 0; w < 8; ++w) s += sm.redS[w][t];
    sm.Sinv[t] = 1.f / s;
  }
  __syncthreads();

  #pragma unroll
  for (int mt = 0; mt < 4; ++mt)
    #pragma unroll
    for (int r = 0; r < 4; ++r) {
      const int row = mt * 16 + q * 4 + r;
      const float inv = sm.Sinv[row];
      #pragma unroll
      for (int nt = 0; nt < 4; ++nt)
        sm.attn[row][lw0 + nt * 16 + c] = (__bf16)(acc[mt][nt][r] * inv);
    }

  const int wM = wv >> 2;
  const int wN = wv & 3;
  f32x4 acc2[2][16];
  #pragma unroll
  for (int i = 0; i < 2; ++i)
    #pragma unroll
    for (int j = 0; j < 16; ++j) acc2[i][j] = fzero;

  for (int lc = 0; lc < 8; ++lc) {
    const int l0c = lc * 64;
    #pragma unroll
    for (int hh = 0; hh < 2; ++hh) {
      __syncthreads();
      {
        const float* xcol = Xb + (size_t)hh * 512 + t;
        #pragma unroll
        for (int u = 0; u < 16; ++u) {
          const int l = l0c + u * 4;
          const float d0 = xcol[(size_t)(l + 0) * HN];
          const float d1 = xcol[(size_t)(l + 1) * HN];
          const float d2 = xcol[(size_t)(l + 2) * HN];
          const float d3 = xcol[(size_t)(l + 3) * HN];
          bf16x4 p;
          p[0] = (__bf16)d0; p[1] = (__bf16)d1; p[2] = (__bf16)d2; p[3] = (__bf16)d3;
          *(bf16x4*)&sm.u.x2[t][u * 4] = p;
        }
      }
      __syncthreads();
      #pragma unroll
      for (int ks = 0; ks < 2; ++ks) {
        bf16x8 aF2[2], bF2[8];
        #pragma unroll
        for (int mt = 0; mt < 2; ++mt)
          aF2[mt] = *(const bf16x8*)&sm.attn[wM * 32 + mt * 16 + c][l0c + ks * 32 + q * 8];
        #pragma unroll
        for (int nt = 0; nt < 8; ++nt)
          bF2[nt] = *(const bf16x8*)&sm.u.x2[wN * 128 + nt * 16 + c][ks * 32 + q * 8];
        #pragma unroll
        for (int mt = 0; mt < 2; ++mt)
          #pragma unroll
          for (int nt = 0; nt < 8; ++nt)
            acc2[mt][hh * 8 + nt] =
                __builtin_amdgcn_mfma_f32_16x16x32_bf16(aF2[mt], bF2[nt], acc2[mt][hh * 8 + nt], 0, 0, 0);
      }
    }
  }

  float* outb = out + ((size_t)b * KN + k0) * HN;
  #pragma unroll
  for (int mt = 0; mt < 2; ++mt) {
    #pragma unroll
    for (int j = 0; j < 16; ++j) {
      const int hh = j >> 3, nt = j & 7;
      const int h = hh * 512 + wN * 128 + nt * 16 + c;
      #pragma unroll
      for (int r = 0; r < 4; ++r) {
        const int krow = wM * 32 + mt * 16 + q * 4 + r;
        outb[(size_t)krow * HN + h] = acc2[mt][j][r];
      }
    }
  }
}

// ---------------- launch ----------------------------------------------------
extern "C" void kernel_launch(void* const* d_in, const int* in_sizes, int n_in,
                              void* d_out, int out_size, void* d_ws, size_t ws_size,
                              hipStream_t stream) {
  (void)in_sizes; (void)n_in; (void)out_size;
  const float* X = (const float*)d_in[0];
  const int* Mk = (const int*)d_in[1];
  const float* W = (const float*)d_in[2];
  float* out = (float*)d_out;

  const size_t need = ((size_t)KN * HN + 2 * (size_t)BN * LN * HN) * sizeof(__bf16);
  if (d_ws == nullptr || ws_size < need) {
    dim3 grid(KN / TK, BN);
    mlattn_fused<<<grid, NTHREADS, 0, stream>>>(X, Mk, W, out);
    return;
  }

  __bf16* Wb = (__bf16*)d_ws;                       // 16 MB
  __bf16* Xbb = Wb + (size_t)KN * HN;               // 16 MB
  __bf16* Xtb = Xbb + (size_t)BN * LN * HN;         // 16 MB

  cvt_w<<<(KN * HN / 4) / 256, 256, 0, stream>>>(W, Wb);
  trans_x<<<dim3(128, BN), 256, 0, stream>>>(X, Xbb, Xtb);
  mlattn_fused2<<<dim3(KN / TK, BN), NTHREADS, 0, stream>>>(Wb, Xbb, Xtb, Mk, out);
}

// Round 3
// 964.614 us; speedup vs baseline: 1.6666x; 1.0380x over previous
//
#include <hip/hip_runtime.h>
#include <stdint.h>

#define BN 16
#define LN 512
#define HN 1024
#define KN 8192
#define TK 64
#define NTHREADS 512

typedef float  f32x4  __attribute__((ext_vector_type(4)));
typedef __bf16 bf16x8 __attribute__((ext_vector_type(8)));
typedef __bf16 bf16x4 __attribute__((ext_vector_type(4)));

// ---------------- async 16B global->LDS (DMA, no VGPR round trip) ----------
__device__ __forceinline__ void cp16(const void* g, void* l) {
  __builtin_amdgcn_global_load_lds(
      (const __attribute__((address_space(1))) unsigned int*)g,
      (__attribute__((address_space(3))) unsigned int*)l, 16, 0, 0);
}

#define SFENCE() __builtin_amdgcn_sched_barrier(0)
#define WAVE_BARRIER() __builtin_amdgcn_s_barrier()

// ---------------- prepass 1: W fp32 -> bf16 --------------------------------
__global__ void cvt_w(const float* __restrict__ W, __bf16* __restrict__ Wb) {
  const size_t i = (size_t)blockIdx.x * blockDim.x + threadIdx.x; // KN*HN/4 threads
  const float4 v = ((const float4*)W)[i];
  bf16x4 o; o[0] = (__bf16)v.x; o[1] = (__bf16)v.y; o[2] = (__bf16)v.z; o[3] = (__bf16)v.w;
  ((bf16x4*)Wb)[i] = o;
}

// ---------------- prepass 2: X -> bf16 X  and  bf16 X^T --------------------
__global__ void trans_x(const float* __restrict__ X, __bf16* __restrict__ Xb,
                        __bf16* __restrict__ Xt) {
  __shared__ __bf16 T[64][72];
  const int b  = blockIdx.y;
  const int l0 = (blockIdx.x & 7) * 64;
  const int h0 = (blockIdx.x >> 3) * 64;
  const int t  = threadIdx.x;
  #pragma unroll
  for (int it = 0; it < 4; ++it) {
    const int idx = it * 256 + t;            // 0..1023
    const int lr = idx >> 4, hc = (idx & 15) << 2;
    const float4 v = *(const float4*)(X + ((size_t)b * LN + l0 + lr) * HN + h0 + hc);
    bf16x4 o; o[0] = (__bf16)v.x; o[1] = (__bf16)v.y; o[2] = (__bf16)v.z; o[3] = (__bf16)v.w;
    *(bf16x4*)(Xb + ((size_t)b * LN + l0 + lr) * HN + h0 + hc) = o;
    *(bf16x4*)&T[lr][hc] = o;
  }
  __syncthreads();
  #pragma unroll
  for (int it = 0; it < 4; ++it) {
    const int idx = it * 256 + t;
    const int hr = idx >> 4, lg = (idx & 15) << 2;
    bf16x4 o;
    o[0] = T[lg + 0][hr]; o[1] = T[lg + 1][hr];
    o[2] = T[lg + 2][hr]; o[3] = T[lg + 3][hr];
    *(bf16x4*)(Xt + ((size_t)b * HN + h0 + hr) * LN + l0 + lg) = o;
  }
}

// ---------------- fused main kernel (counted-vmcnt pipeline) ---------------
// Staged LDS tiles are LINEAR (global_load_lds constraint); ds_read bank
// conflicts fixed by XOR-swizzling the 16B slot index, inverse permutation
// folded into the GLOBAL source address (both-sides rule).
//   phase-1 (8 slots/row):  jj' = jj ^ (row&7)
//   phase-2 (4 slots/row):  jj' = jj ^ ((row>>1)&3)
// Main loops use raw s_barrier + counted s_waitcnt vmcnt(N) (N = loads of
// the NEXT tile kept in flight across the barrier) — never vmcnt(0).
#define P2_AT_LDA 520

struct __align__(16) P1Mem {
  __bf16 xs[2][512 * 64];     // 2 x 65,536 B
  __bf16 wt[2][64 * 64];      // 2 x  8,192 B   => 147,456 B
};
struct __align__(16) P2Mem {
  __bf16 attn[TK][P2_AT_LDA]; // 66,560 B
  __bf16 xt[2][512 * 32];     // 2 x 32,768 B   => 132,096 B
};
struct __align__(16) SMem {
  union {
    P1Mem p1;
    P2Mem p2;
    float osm[TK * 516];      // 132,096 B epilogue staging
  } u;
  float redM[8][TK];
  float redS[8][TK];
  float Mf[TK];
  float Sinv[TK];
};                            // 152,064 B < 160 KiB

__device__ __forceinline__ void p1_mfma(const __bf16* __restrict__ wtb,
                                        const __bf16* __restrict__ xsb,
                                        int c, int q, int lw0,
                                        f32x4 (&acc)[4][4]) {
  #pragma unroll
  for (int ks = 0; ks < 2; ++ks) {
    bf16x8 aF[4], bF[4];
    #pragma unroll
    for (int mt = 0; mt < 4; ++mt) {
      const int r = mt * 16 + c;
      aF[mt] = *(const bf16x8*)&wtb[r * 64 + (((ks * 4 + q) ^ (c & 7)) << 3)];
    }
    #pragma unroll
    for (int nt = 0; nt < 4; ++nt) {
      const int r = lw0 + nt * 16 + c;
      bF[nt] = *(const bf16x8*)&xsb[r * 64 + (((ks * 4 + q) ^ (c & 7)) << 3)];
    }
    #pragma unroll
    for (int mt = 0; mt < 4; ++mt)
      #pragma unroll
      for (int nt = 0; nt < 4; ++nt)
        acc[mt][nt] = __builtin_amdgcn_mfma_f32_16x16x32_bf16(aF[mt], bF[nt], acc[mt][nt], 0, 0, 0);
  }
}

template <int HH>
__device__ __forceinline__ void p2_mfma(const __bf16 (*attn)[P2_AT_LDA],
                                        const __bf16* __restrict__ xtb,
                                        int c, int q, int wM, int wN, int l0c,
                                        int swq8, f32x4 (&acc2)[2][16]) {
  bf16x8 aF2[2], bF2[8];
  #pragma unroll
  for (int mt = 0; mt < 2; ++mt)
    aF2[mt] = *(const bf16x8*)&attn[wM * 32 + mt * 16 + c][l0c + q * 8];
  #pragma unroll
  for (int nt = 0; nt < 8; ++nt) {
    const int r = wN * 128 + nt * 16 + c;
    bF2[nt] = *(const bf16x8*)&xtb[r * 32 + swq8];
  }
  #pragma unroll
  for (int mt = 0; mt < 2; ++mt)
    #pragma unroll
    for (int nt = 0; nt < 8; ++nt)
      acc2[mt][HH * 8 + nt] =
          __builtin_amdgcn_mfma_f32_16x16x32_bf16(aF2[mt], bF2[nt], acc2[mt][HH * 8 + nt], 0, 0, 0);
}

__global__ __launch_bounds__(NTHREADS, 1)
void mlattn_fused2(const __bf16* __restrict__ Wb, const __bf16* __restrict__ Xb,
                   const __bf16* __restrict__ Xt, const int* __restrict__ Mk,
                   float* __restrict__ out) {
  __shared__ SMem sm;
  const int t    = threadIdx.x;
  const int wv   = t >> 6;
  const int lane = t & 63;
  const int q    = lane >> 4;
  const int c    = lane & 15;
  const int b    = blockIdx.y;
  const int k0   = blockIdx.x * TK;
  const __bf16* Xbb = Xb + (size_t)b * LN * HN;
  const __bf16* Xtb = Xt + (size_t)b * HN * LN;
  const f32x4 fzero = {0.f, 0.f, 0.f, 0.f};
  const int lw0 = wv * 64;

  // -------- Mk preload: force completion BEFORE any cp16 enters vmcnt FIFO -
  int mkv[4];
  #pragma unroll
  for (int nt = 0; nt < 4; ++nt) mkv[nt] = Mk[b * LN + lw0 + nt * 16 + c];
  asm volatile("" : "+v"(mkv[0]), "+v"(mkv[1]), "+v"(mkv[2]), "+v"(mkv[3]));

  // -------- per-thread staging bases (swizzle folded into global src) ------
  const int tr8 = t >> 3, tc8 = t & 7;
  const int colOff1 = ((tc8 ^ (tr8 & 7)) << 3);
  const __bf16* xsrc = Xbb + (size_t)tr8 * HN + colOff1;
  const __bf16* wsrc = Wb + (size_t)(k0 + tr8) * HN + colOff1;
  const int tr4 = t >> 2, tc4 = t & 3;
  const int colOff2 = ((tc4 ^ ((t >> 3) & 3)) << 3);
  const __bf16* tsrc = Xtb + (size_t)tr4 * LN + colOff2;

  // ===== Phase 1: S[64][512] = W_tile . Xb^T (contract h) ===================
  // tile n lives in buffer ((n+1)&1): tile0->buf1, ..., tile15->buf0.
  f32x4 acc[4][4];
  #pragma unroll
  for (int mt = 0; mt < 4; ++mt)
    #pragma unroll
    for (int nt = 0; nt < 4; ++nt) acc[mt][nt] = fzero;

  // prologue: stage tile 0 into buffer 1
  cp16(wsrc, &sm.u.p1.wt[1][t * 8]);
  #pragma unroll
  for (int i = 0; i < 8; ++i)
    cp16(xsrc + (size_t)i * 64 * HN, &sm.u.p1.xs[1][(i * 512 + t) * 8]);
  SFENCE();

  #pragma unroll 1
  for (int tt = 0; tt < 15; ++tt) {
    const int bc = (tt + 1) & 1;          // buffer holding tile tt
    const int h0 = (tt + 1) * 64;
    // issue tile tt+1 into the other buffer (stays in flight across barrier)
    cp16(wsrc + h0, &sm.u.p1.wt[bc ^ 1][t * 8]);
    #pragma unroll
    for (int i = 0; i < 8; ++i)
      cp16(xsrc + (size_t)i * 64 * HN + h0, &sm.u.p1.xs[bc ^ 1][(i * 512 + t) * 8]);
    SFENCE();
    asm volatile("s_waitcnt vmcnt(9)" ::: "memory");   // tile tt landed; tt+1 in flight
    SFENCE();
    WAVE_BARRIER();
    SFENCE();
    __builtin_amdgcn_s_setprio(1);
    p1_mfma(sm.u.p1.wt[bc], sm.u.p1.xs[bc], c, q, lw0, acc);
    __builtin_amdgcn_s_setprio(0);
    SFENCE();
    WAVE_BARRIER();                        // buf bc free for overwrite next iter
    SFENCE();
  }
  // tail (tile15 in buf0): overlap phase-2 xt tile0 prefetch with compute.
  // xt[0] bytes overlap xs[1] only (last read at step 14) -- safe.
  #pragma unroll
  for (int i = 0; i < 4; ++i)
    cp16(tsrc + (size_t)i * 128 * LN, &sm.u.p2.xt[0][(i * 512 + t) * 8]);
  SFENCE();
  asm volatile("s_waitcnt vmcnt(4)" ::: "memory");     // tile15 landed; xt0 in flight
  SFENCE();
  WAVE_BARRIER();
  SFENCE();
  __builtin_amdgcn_s_setprio(1);
  p1_mfma(sm.u.p1.wt[0], sm.u.p1.xs[0], c, q, lw0, acc);
  __builtin_amdgcn_s_setprio(0);
  // no barrier needed here: softmax touches registers + redM/redS (disjoint
  // from all phase-1 LDS); its first __syncthreads orders waves.

  // ===== mask + softmax over l (verified) ===================================
  #pragma unroll
  for (int nt = 0; nt < 4; ++nt) {
    if (!mkv[nt]) {
      #pragma unroll
      for (int mt = 0; mt < 4; ++mt)
        #pragma unroll
        for (int r = 0; r < 4; ++r) acc[mt][nt][r] = -1e30f;
    }
  }
  float pm[4][4];
  #pragma unroll
  for (int mt = 0; mt < 4; ++mt)
    #pragma unroll
    for (int r = 0; r < 4; ++r)
      pm[mt][r] = fmaxf(fmaxf(acc[mt][0][r], acc[mt][1][r]), fmaxf(acc[mt][2][r], acc[mt][3][r]));
  #pragma unroll
  for (int off = 1; off < 16; off <<= 1)
    #pragma unroll
    for (int mt = 0; mt < 4; ++mt)
      #pragma unroll
      for (int r = 0; r < 4; ++r)
        pm[mt][r] = fmaxf(pm[mt][r], __shfl_xor(pm[mt][r], off, 64));
  if (c == 0) {
    #pragma unroll
    for (int mt = 0; mt < 4; ++mt)
      #pragma unroll
      for (int r = 0; r < 4; ++r) sm.redM[wv][mt * 16 + q * 4 + r] = pm[mt][r];
  }
  __syncthreads();
  if (t < TK) {
    float m = sm.redM[0][t];
    #pragma unroll
    for (int w = 1; w < 8; ++w) m = fmaxf(m, sm.redM[w][t]);
    sm.Mf[t] = m;
  }
  __syncthreads();

  float ps[4][4];
  #pragma unroll
  for (int mt = 0; mt < 4; ++mt)
    #pragma unroll
    for (int r = 0; r < 4; ++r) {
      const float M = sm.Mf[mt * 16 + q * 4 + r];
      float s = 0.f;
      #pragma unroll
      for (int nt = 0; nt < 4; ++nt) {
        const float e = __expf(acc[mt][nt][r] - M);
        acc[mt][nt][r] = e;
        s += e;
      }
      ps[mt][r] = s;
    }
  #pragma unroll
  for (int off = 1; off < 16; off <<= 1)
    #pragma unroll
    for (int mt = 0; mt < 4; ++mt)
      #pragma unroll
      for (int r = 0; r < 4; ++r) ps[mt][r] += __shfl_xor(ps[mt][r], off, 64);
  if (c == 0) {
    #pragma unroll
    for (int mt = 0; mt < 4; ++mt)
      #pragma unroll
      for (int r = 0; r < 4; ++r) sm.redS[wv][mt * 16 + q * 4 + r] = ps[mt][r];
  }
  __syncthreads();
  if (t < TK) {
    float s = 0.f;
    #pragma unroll
    for (int w = 0; w < 8; ++w) s += sm.redS[w][t];
    sm.Sinv[t] = 1.f / s;
  }
  __syncthreads();

  // normalized attn -> LDS (A-operand layout, full 64x512 tile)
  #pragma unroll
  for (int mt = 0; mt < 4; ++mt)
    #pragma unroll
    for (int r = 0; r < 4; ++r) {
      const int row = mt * 16 + q * 4 + r;
      const float inv = sm.Sinv[row];
      #pragma unroll
      for (int nt = 0; nt < 4; ++nt)
        sm.u.p2.attn[row][lw0 + nt * 16 + c] = (__bf16)(acc[mt][nt][r] * inv);
    }
  __syncthreads();   // attn visible to all waves

  // ===== Phase 2: O[64][1024] = attn . Xb (contract l) =====================
  // step s: l-chunk = (s>>1)*32, h-half = s&1; tile s in xt[s&1].
  const int wM = wv >> 2;
  const int wN = wv & 3;
  const int swq8 = ((q ^ ((c >> 1) & 3)) << 3);
  f32x4 acc2[2][16];
  #pragma unroll
  for (int i = 0; i < 2; ++i)
    #pragma unroll
    for (int j = 0; j < 16; ++j) acc2[i][j] = fzero;

#define P2STEP(BUF, S)                                                          \
  {                                                                             \
    const int sn_ = (S) + 1;                                                    \
    const __bf16* src_ =                                                        \
        tsrc + (size_t)((sn_ & 1) * 512) * LN + ((sn_ >> 1) << 5);              \
    _Pragma("unroll")                                                           \
    for (int i_ = 0; i_ < 4; ++i_)                                              \
      cp16(src_ + (size_t)i_ * 128 * LN,                                        \
           &sm.u.p2.xt[(BUF) ^ 1][(i_ * 512 + t) * 8]);                         \
    SFENCE();                                                                   \
    asm volatile("s_waitcnt vmcnt(4)" ::: "memory");                            \
    SFENCE();                                                                   \
    WAVE_BARRIER();                                                             \
    SFENCE();                                                                   \
    __builtin_amdgcn_s_setprio(1);                                              \
    p2_mfma<(BUF)>(sm.u.p2.attn, sm.u.p2.xt[(BUF)], c, q, wM, wN,               \
                   ((S) >> 1) << 5, swq8, acc2);                                \
    __builtin_amdgcn_s_setprio(0);                                              \
    SFENCE();                                                                   \
    WAVE_BARRIER();                                                             \
    SFENCE();                                                                   \
  }

  #pragma unroll 1
  for (int s = 0; s < 30; s += 2) {
    P2STEP(0, s);
    P2STEP(1, s + 1);
  }
  P2STEP(0, 30);
  // s = 31: no further prefetch; drain and compute last tile.
  asm volatile("s_waitcnt vmcnt(0)" ::: "memory");
  SFENCE();
  WAVE_BARRIER();
  SFENCE();
  __builtin_amdgcn_s_setprio(1);
  p2_mfma<1>(sm.u.p2.attn, sm.u.p2.xt[1], c, q, wM, wN, 480, swq8, acc2);
  __builtin_amdgcn_s_setprio(0);
  __syncthreads();   // all reads done before epilogue overwrites LDS
#undef P2STEP

  // ===== epilogue: LDS round-trip -> full-line dwordx4 stores ===============
  float* outb = out + ((size_t)b * KN + k0) * HN;
  #pragma unroll
  for (int hh = 0; hh < 2; ++hh) {
    if (hh) __syncthreads();
    #pragma unroll
    for (int mt = 0; mt < 2; ++mt)
      #pragma unroll
      for (int nt = 0; nt < 8; ++nt) {
        const int hl = wN * 128 + nt * 16 + c;
        #pragma unroll
        for (int r = 0; r < 4; ++r) {
          const int krow = wM * 32 + mt * 16 + q * 4 + r;
          sm.u.osm[krow * 516 + hl] = acc2[mt][hh * 8 + nt][r];
        }
      }
    __syncthreads();
    #pragma unroll
    for (int i = 0; i < 16; ++i) {
      const int s = i * 512 + t;
      const int row = s >> 7, col4 = s & 127;
      *(f32x4*)(outb + (size_t)row * HN + hh * 512 + (col4 << 2)) =
          *(const f32x4*)&sm.u.osm[row * 516 + (col4 << 2)];
    }
  }
}

// ---------------- fallback (previous verified kernel) ----------------------
#define XT_LDA 72
#define WT_LDA 72
#define AT_LDA_O 520
#define X2_LDA 72

struct __align__(16) SMemOld {
  __bf16 attn[TK][AT_LDA_O];
  union {
    struct { __bf16 xt[LN][XT_LDA]; __bf16 wt[TK][WT_LDA]; } p1;
    __bf16 x2[512][X2_LDA];
  } u;
  float redM[8][TK];
  float redS[8][TK];
  float Mf[TK];
  float Sinv[TK];
};

__device__ __forceinline__ bf16x4 cvt4o(float4 v) {
  bf16x4 r;
  r[0] = (__bf16)v.x; r[1] = (__bf16)v.y; r[2] = (__bf16)v.z; r[3] = (__bf16)v.w;
  return r;
}

__global__ __launch_bounds__(NTHREADS, 2)
void mlattn_fused(const float* __restrict__ X, const int* __restrict__ Mk,
                  const float* __restrict__ W, float* __restrict__ out) {
  __shared__ SMemOld sm;
  const int t    = threadIdx.x;
  const int wv   = t >> 6;
  const int lane = t & 63;
  const int q    = lane >> 4;
  const int c    = lane & 15;
  const int b    = blockIdx.y;
  const int k0   = blockIdx.x * TK;
  const float* Xb = X + (size_t)b * LN * HN;
  const f32x4 fzero = {0.f, 0.f, 0.f, 0.f};

  f32x4 acc[4][4];
  #pragma unroll
  for (int mt = 0; mt < 4; ++mt)
    #pragma unroll
    for (int nt = 0; nt < 4; ++nt) acc[mt][nt] = fzero;

  const int lw0 = wv * 64;
  const int sr  = t >> 4;
  const int sc  = t & 15;

  for (int h0 = 0; h0 < HN; h0 += 64) {
    #pragma unroll
    for (int p = 0; p < 2; ++p) {
      const int row = p * 32 + sr;
      float4 v = *(const float4*)(W + (size_t)(k0 + row) * HN + h0 + sc * 4);
      *(bf16x4*)&sm.u.p1.wt[row][sc * 4] = cvt4o(v);
    }
    #pragma unroll
    for (int p = 0; p < 16; ++p) {
      const int row = p * 32 + sr;
      float4 v = *(const float4*)(Xb + (size_t)row * HN + h0 + sc * 4);
      *(bf16x4*)&sm.u.p1.xt[row][sc * 4] = cvt4o(v);
    }
    __syncthreads();
    #pragma unroll
    for (int ks = 0; ks < 2; ++ks) {
      bf16x8 aF[4], bF[4];
      #pragma unroll
      for (int mt = 0; mt < 4; ++mt)
        aF[mt] = *(const bf16x8*)&sm.u.p1.wt[mt * 16 + c][ks * 32 + q * 8];
      #pragma unroll
      for (int nt = 0; nt < 4; ++nt)
        bF[nt] = *(const bf16x8*)&sm.u.p1.xt[lw0 + nt * 16 + c][ks * 32 + q * 8];
      #pragma unroll
      for (int mt = 0; mt < 4; ++mt)
        #pragma unroll
        for (int nt = 0; nt < 4; ++nt)
          acc[mt][nt] = __builtin_amdgcn_mfma_f32_16x16x32_bf16(aF[mt], bF[nt], acc[mt][nt], 0, 0, 0);
    }
    __syncthreads();
  }

  #pragma unroll
  for (int nt = 0; nt < 4; ++nt) {
    const int m = Mk[b * LN + lw0 + nt * 16 + c];
    if (!m) {
      #pragma unroll
      for (int mt = 0; mt < 4; ++mt)
        #pragma unroll
        for (int r = 0; r < 4; ++r) acc[mt][nt][r] = -1e30f;
    }
  }

  float pm[4][4];
  #pragma unroll
  for (int mt = 0; mt < 4; ++mt)
    #pragma unroll
    for (int r = 0; r < 4; ++r)
      pm[mt][r] = fmaxf(fmaxf(acc[mt][0][r], acc[mt][1][r]), fmaxf(acc[mt][2][r], acc[mt][3][r]));
  #pragma unroll
  for (int off = 1; off < 16; off <<= 1)
    #pragma unroll
    for (int mt = 0; mt < 4; ++mt)
      #pragma unroll
      for (int r = 0; r < 4; ++r)
        pm[mt][r] = fmaxf(pm[mt][r], __shfl_xor(pm[mt][r], off, 64));
  if (c == 0) {
    #pragma unroll
    for (int mt = 0; mt < 4; ++mt)
      #pragma unroll
      for (int r = 0; r < 4; ++r) sm.redM[wv][mt * 16 + q * 4 + r] = pm[mt][r];
  }
  __syncthreads();
  if (t < TK) {
    float m = sm.redM[0][t];
    #pragma unroll
    for (int w = 1; w < 8; ++w) m = fmaxf(m, sm.redM[w][t]);
    sm.Mf[t] = m;
  }
  __syncthreads();

  float ps[4][4];
  #pragma unroll
  for (int mt = 0; mt < 4; ++mt)
    #pragma unroll
    for (int r = 0; r < 4; ++r) {
      const float M = sm.Mf[mt * 16 + q * 4 + r];
      float s = 0.f;
      #pragma unroll
      for (int nt = 0; nt < 4; ++nt) {
        const float e = __expf(acc[mt][nt][r] - M);
        acc[mt][nt][r] = e;
        s += e;
      }
      ps[mt][r] = s;
    }
  #pragma unroll
  for (int off = 1; off < 16; off <<= 1)
    #pragma unroll
    for (int mt = 0; mt < 4; ++mt)
      #pragma unroll
      for (int r = 0; r < 4; ++r) ps[mt][r] += __shfl_xor(ps[mt][r], off, 64);
  if (c == 0) {
    #pragma unroll
    for (int mt = 0; mt < 4; ++mt)
      #pragma unroll
      for (int r = 0; r < 4; ++r) sm.redS[wv][mt * 16 + q * 4 + r] = ps[mt][r];
  }
  __syncthreads();
  if (t < TK) {
    float s = 0.f;
    #pragma unroll
    for (int w = 0; w < 8; ++w) s += sm.redS[w][t];
    sm.Sinv[t] = 1.f / s;
  }
  __syncthreads();

  #pragma unroll
  for (int mt = 0; mt < 4; ++mt)
    #pragma unroll
    for (int r = 0; r < 4; ++r) {
      const int row = mt * 16 + q * 4 + r;
      const float inv = sm.Sinv[row];
      #pragma unroll
      for (int nt = 0; nt < 4; ++nt)
        sm.attn[row][lw0 + nt * 16 + c] = (__bf16)(acc[mt][nt][r] * inv);
    }

  const int wM = wv >> 2;
  const int wN = wv & 3;
  f32x4 acc2[2][16];
  #pragma unroll
  for (int i = 0; i < 2; ++i)
    #pragma unroll
    for (int j = 0; j < 16; ++j) acc2[i][j] = fzero;

  for (int lc = 0; lc < 8; ++lc) {
    const int l0c = lc * 64;
    #pragma unroll
    for (int hh = 0; hh < 2; ++hh) {
      __syncthreads();
      {
        const float* xcol = Xb + (size_t)hh * 512 + t;
        #pragma unroll
        for (int u = 0; u < 16; ++u) {
          const int l = l0c + u * 4;
          const float d0 = xcol[(size_t)(l + 0) * HN];
          const float d1 = xcol[(size_t)(l + 1) * HN];
          const float d2 = xcol[(size_t)(l + 2) * HN];
          const float d3 = xcol[(size_t)(l + 3) * HN];
          bf16x4 p;
          p[0] = (__bf16)d0; p[1] = (__bf16)d1; p[2] = (__bf16)d2; p[3] = (__bf16)d3;
          *(bf16x4*)&sm.u.x2[t][u * 4] = p;
        }
      }
      __syncthreads();
      #pragma unroll
      for (int ks = 0; ks < 2; ++ks) {
        bf16x8 aF2[2], bF2[8];
        #pragma unroll
        for (int mt = 0; mt < 2; ++mt)
          aF2[mt] = *(const bf16x8*)&sm.attn[wM * 32 + mt * 16 + c][l0c + ks * 32 + q * 8];
        #pragma unroll
        for (int nt = 0; nt < 8; ++nt)
          bF2[nt] = *(const bf16x8*)&sm.u.x2[wN * 128 + nt * 16 + c][ks * 32 + q * 8];
        #pragma unroll
        for (int mt = 0; mt < 2; ++mt)
          #pragma unroll
          for (int nt = 0; nt < 8; ++nt)
            acc2[mt][hh * 8 + nt] =
                __builtin_amdgcn_mfma_f32_16x16x32_bf16(aF2[mt], bF2[nt], acc2[mt][hh * 8 + nt], 0, 0, 0);
      }
    }
  }

  float* outb = out + ((size_t)b * KN + k0) * HN;
  #pragma unroll
  for (int mt = 0; mt < 2; ++mt) {
    #pragma unroll
    for (int j = 0; j < 16; ++j) {
      const int hh = j >> 3, nt = j & 7;
      const int h = hh * 512 + wN * 128 + nt * 16 + c;
      #pragma unroll
      for (int r = 0; r < 4; ++r) {
        const int krow = wM * 32 + mt * 16 + q * 4 + r;
        outb[(size_t)krow * HN + h] = acc2[mt][j][r];
      }
    }
  }
}

// ---------------- launch ----------------------------------------------------
extern "C" void kernel_launch(void* const* d_in, const int* in_sizes, int n_in,
                              void* d_out, int out_size, void* d_ws, size_t ws_size,
                              hipStream_t stream) {
  (void)in_sizes; (void)n_in; (void)out_size;
  const float* X = (const float*)d_in[0];
  const int* Mk = (const int*)d_in[1];
  const float* W = (const float*)d_in[2];
  float* out = (float*)d_out;

  const size_t need = ((size_t)KN * HN + 2 * (size_t)BN * LN * HN) * sizeof(__bf16);
  if (d_ws == nullptr || ws_size < need) {
    dim3 grid(KN / TK, BN);
    mlattn_fused<<<grid, NTHREADS, 0, stream>>>(X, Mk, W, out);
    return;
  }

  __bf16* Wb = (__bf16*)d_ws;                       // 16 MB
  __bf16* Xbb = Wb + (size_t)KN * HN;               // 16 MB
  __bf16* Xtb = Xbb + (size_t)BN * LN * HN;         // 16 MB

  cvt_w<<<(KN * HN / 4) / 256, 256, 0, stream>>>(W, Wb);
  trans_x<<<dim3(128, BN), 256, 0, stream>>>(X, Xbb, Xtb);
  mlattn_fused2<<<dim3(KN / TK, BN), NTHREADS, 0, stream>>>(Wb, Xbb, Xtb, Mk, out);
}